// Round 1
// baseline (339.037 us; speedup 1.0000x reference)
//
#include <hip/hip_runtime.h>
#include <stdint.h>

// Gaussian kernel matrix: K[i][j] = exp(-||x_i - x_j||^2 / 2), X: [N=16384][D=64] fp32.
// Strategy: bf16 MFMA Gram matrix (K-dim = 64 = 2 MFMA K-steps), no LDS (X is L2-resident),
// epilogue fuses norms + exp. Row norms computed from the SAME bf16-rounded fragments so the
// diagonal cancels exactly; diagonal additionally forced to 1.0.

typedef __attribute__((ext_vector_type(8))) short s16x8;   // 8 bf16 = 4 VGPRs (MFMA A/B frag)
typedef __attribute__((ext_vector_type(4))) float f32x4;   // MFMA C/D frag

#define DDIM 64

// fp32 -> bf16 round-to-nearest-even on the bit pattern; also accumulates H^2 for row norms.
__device__ inline short cvt_rne(float x, float& sq) {
  uint32_t u = __builtin_bit_cast(uint32_t, x);
  uint32_t r = (u + 0x7fffu + ((u >> 16) & 1u)) & 0xffff0000u;
  float hf = __builtin_bit_cast(float, r);
  sq += hf * hf;
  return (short)(r >> 16);
}

__global__ __launch_bounds__(256) void gauss_gram_kernel(
    const float* __restrict__ X, float* __restrict__ K, int n) {
  const int lane = threadIdx.x & 63;
  const int wid  = threadIdx.x >> 6;   // 4 waves: 2x2 over the 128x128 tile
  const int wr = wid >> 1;
  const int wc = wid & 1;
  const int l15 = lane & 15;
  const int lq  = lane >> 4;           // 0..3

  const int i0 = blockIdx.x * 128 + wr * 64;   // row block (A rows)
  const int j0 = blockIdx.y * 128 + wc * 64;   // col block (B rows = X rows)

  s16x8 a[4][2], b[4][2];
  float rnA[4], rnB[4];

  // ---- load A fragments (rows i0 + mi*16 + l15), convert fp32->bf16, norm accumulate ----
#pragma unroll
  for (int mi = 0; mi < 4; ++mi) {
    float s = 0.f;
#pragma unroll
    for (int ks = 0; ks < 2; ++ks) {
      const f32x4* p = reinterpret_cast<const f32x4*>(
          X + (size_t)(i0 + mi * 16 + l15) * DDIM + ks * 32 + lq * 8);
      f32x4 v0 = p[0];
      f32x4 v1 = p[1];
      s16x8 h;
      h[0] = cvt_rne(v0[0], s); h[1] = cvt_rne(v0[1], s);
      h[2] = cvt_rne(v0[2], s); h[3] = cvt_rne(v0[3], s);
      h[4] = cvt_rne(v1[0], s); h[5] = cvt_rne(v1[1], s);
      h[6] = cvt_rne(v1[2], s); h[7] = cvt_rne(v1[3], s);
      a[mi][ks] = h;
    }
    // full row norm: sum across the 4 lane-groups holding this row's k-chunks
    s += __shfl_xor(s, 16);
    s += __shfl_xor(s, 32);
    rnA[mi] = s;   // lane l holds rn of row (i0 + mi*16 + (l&15)), replicated over lq
  }

  // ---- load B fragments (rows j0 + ni*16 + l15) ----
#pragma unroll
  for (int ni = 0; ni < 4; ++ni) {
    float s = 0.f;
#pragma unroll
    for (int ks = 0; ks < 2; ++ks) {
      const f32x4* p = reinterpret_cast<const f32x4*>(
          X + (size_t)(j0 + ni * 16 + l15) * DDIM + ks * 32 + lq * 8);
      f32x4 v0 = p[0];
      f32x4 v1 = p[1];
      s16x8 h;
      h[0] = cvt_rne(v0[0], s); h[1] = cvt_rne(v0[1], s);
      h[2] = cvt_rne(v0[2], s); h[3] = cvt_rne(v0[3], s);
      h[4] = cvt_rne(v1[0], s); h[5] = cvt_rne(v1[1], s);
      h[6] = cvt_rne(v1[2], s); h[7] = cvt_rne(v1[3], s);
      b[ni][ks] = h;
    }
    s += __shfl_xor(s, 16);
    s += __shfl_xor(s, 32);
    rnB[ni] = s;   // lane l holds rn of col (j0 + ni*16 + (l&15))
  }

  // ---- MFMA: acc[mi][ni] = sum_k A[i][k] * B[j][k]  (Gram; both operands from X rows) ----
  f32x4 acc[4][4] = {};
#pragma unroll
  for (int ks = 0; ks < 2; ++ks)
#pragma unroll
    for (int mi = 0; mi < 4; ++mi)
#pragma unroll
      for (int ni = 0; ni < 4; ++ni)
        acc[mi][ni] = __builtin_amdgcn_mfma_f32_16x16x32_bf16(
            a[mi][ks], b[ni][ks], acc[mi][ni], 0, 0, 0);

  // ---- epilogue: D2 = rn_i + rn_j - 2*dot; K = exp(-D2/2) = exp2(-D2 * 1/(2 ln2)) ----
  // C/D layout (verified m89): col = lane&15, row = (lane>>4)*4 + reg
#pragma unroll
  for (int mi = 0; mi < 4; ++mi) {
    float rrow[4];
#pragma unroll
    for (int r = 0; r < 4; ++r)
      rrow[r] = __shfl(rnA[mi], lq * 4 + r);   // rn of row (i0 + mi*16 + lq*4 + r)
#pragma unroll
    for (int ni = 0; ni < 4; ++ni) {
#pragma unroll
      for (int r = 0; r < 4; ++r) {
        const int rg = i0 + mi * 16 + lq * 4 + r;
        const int cg = j0 + ni * 16 + l15;
        float d2 = rrow[r] + rnB[ni] - 2.0f * acc[mi][ni][r];
        d2 = fmaxf(d2, 0.0f);
        float val = (rg == cg) ? 1.0f : exp2f(-0.72134752044f * d2);
        K[(size_t)rg * n + cg] = val;
      }
    }
  }
}

extern "C" void kernel_launch(void* const* d_in, const int* in_sizes, int n_in,
                              void* d_out, int out_size, void* d_ws, size_t ws_size,
                              hipStream_t stream) {
  (void)n_in; (void)d_ws; (void)ws_size; (void)out_size;
  const float* X = (const float*)d_in[0];
  float* K = (float*)d_out;
  const int n = in_sizes[0] / DDIM;   // 16384
  dim3 grid(n / 128, n / 128);
  gauss_gram_kernel<<<grid, 256, 0, stream>>>(X, K, n);
}

// Round 2
// 316.144 us; speedup vs baseline: 1.0724x; 1.0724x over previous
//
#include <hip/hip_runtime.h>
#include <stdint.h>

// Gaussian kernel matrix K[i][j] = exp(-||x_i-x_j||^2/2), X: [16384][64] fp32.
// R2: A-resident strip mining (JT col-tiles per block, A frags + norms stay in
// registers), swapped-operand MFMA so each lane's 4 acc regs are 4 consecutive
// output COLUMNS -> float4 stores. Norms computed from the same bf16-rounded
// fragments so the diagonal cancels exactly; diagonal also forced to 1.0.

typedef __attribute__((ext_vector_type(8))) short s16x8;   // 8 bf16 (MFMA A/B frag)
typedef __attribute__((ext_vector_type(4))) float f32x4;   // MFMA C/D frag

#define DDIM 64
#define JT 8   // column tiles per block; grid.y = N/(128*JT)

// fp32 -> bf16 RNE on the bit pattern; accumulates rounded value^2 for norms.
__device__ inline short cvt_rne(float x, float& sq) {
  uint32_t u = __builtin_bit_cast(uint32_t, x);
  uint32_t r = (u + 0x7fffu + ((u >> 16) & 1u)) & 0xffff0000u;
  float hf = __builtin_bit_cast(float, r);
  sq += hf * hf;
  return (short)(r >> 16);
}

// Load one 16-row MFMA fragment pair (K=64 -> 2 k-steps) for rows base+l15,
// k-chunk lq*8 within each 32-wide k-step. Also produces the full row norm
// (replicated across the 4 lq groups).
__device__ inline void load_frag(const float* __restrict__ X, int row, int lq,
                                 s16x8 h2[2], float& rn) {
  float s = 0.f;
#pragma unroll
  for (int ks = 0; ks < 2; ++ks) {
    const f32x4* p = reinterpret_cast<const f32x4*>(
        X + (size_t)row * DDIM + ks * 32 + lq * 8);
    f32x4 v0 = p[0], v1 = p[1];
    s16x8 h;
    h[0] = cvt_rne(v0[0], s); h[1] = cvt_rne(v0[1], s);
    h[2] = cvt_rne(v0[2], s); h[3] = cvt_rne(v0[3], s);
    h[4] = cvt_rne(v1[0], s); h[5] = cvt_rne(v1[1], s);
    h[6] = cvt_rne(v1[2], s); h[7] = cvt_rne(v1[3], s);
    h2[ks] = h;
  }
  s += __shfl_xor(s, 16);
  s += __shfl_xor(s, 32);
  rn = s;
}

__global__ __launch_bounds__(256, 2) void gauss_gram_kernel(
    const float* __restrict__ X, float* __restrict__ K, int n) {
  const int lane = threadIdx.x & 63;
  const int wid  = threadIdx.x >> 6;   // 4 waves: 2x2 over the 128x128 tile
  const int wr = wid >> 1;
  const int wc = wid & 1;
  const int l15 = lane & 15;
  const int lq  = lane >> 4;           // 0..3

  const int i0     = blockIdx.x * 128 + wr * 64;    // output row base (this wave)
  const int jstrip = blockIdx.y * (128 * JT);       // column strip base

  // ---- A fragments + row norms: resident across the whole strip ----
  s16x8 a[4][2]; float rnA[4];
#pragma unroll
  for (int mi = 0; mi < 4; ++mi)
    load_frag(X, i0 + mi * 16 + l15, lq, a[mi], rnA[mi]);
  // rnA[mi] at lane l == norm of row (i0+mi*16+l15) == this lane's output row. No shfl needed.

  for (int jt = 0; jt < JT; ++jt) {
    const int j0 = jstrip + jt * 128 + wc * 64;

    // ---- B fragments + col norms for this tile ----
    s16x8 b[4][2]; float rnB[4];
#pragma unroll
    for (int ni = 0; ni < 4; ++ni)
      load_frag(X, j0 + ni * 16 + l15, lq, b[ni], rnB[ni]);

    // col norm for output col (j0+ni*16+lq*4+r): take from lane (lq*4+r)
    float rcol[4][4];
#pragma unroll
    for (int ni = 0; ni < 4; ++ni)
#pragma unroll
      for (int r = 0; r < 4; ++r)
        rcol[ni][r] = __shfl(rnB[ni], lq * 4 + r);

    // ---- MFMA with SWAPPED operands: D(m=j-idx, n=i-idx) ----
    // C/D layout: n(col)=lane&15 -> output ROW; m(row)=lq*4+reg -> output COL.
    // => lane l, acc[mi][ni] holds K[i0+mi*16+l15][j0+ni*16+lq*4 + reg] : 4 consecutive cols.
    f32x4 acc[4][4] = {};
#pragma unroll
    for (int ks = 0; ks < 2; ++ks)
#pragma unroll
      for (int mi = 0; mi < 4; ++mi)
#pragma unroll
        for (int ni = 0; ni < 4; ++ni)
          acc[mi][ni] = __builtin_amdgcn_mfma_f32_16x16x32_bf16(
              b[ni][ks], a[mi][ks], acc[mi][ni], 0, 0, 0);

    // ---- epilogue: D2 = rn_i + rn_j - 2*dot; K = exp2(-D2/(2 ln2)); float4 stores ----
#pragma unroll
    for (int mi = 0; mi < 4; ++mi) {
      const int rg = i0 + mi * 16 + l15;
      float* rowp = K + (size_t)rg * n;
#pragma unroll
      for (int ni = 0; ni < 4; ++ni) {
        const int c0 = j0 + ni * 16 + lq * 4;
        f32x4 v;
#pragma unroll
        for (int r = 0; r < 4; ++r) {
          float d2 = rnA[mi] + rcol[ni][r] - 2.0f * acc[mi][ni][r];
          d2 = fmaxf(d2, 0.0f);
          v[r] = (rg == c0 + r) ? 1.0f : exp2f(-0.72134752044f * d2);
        }
        *reinterpret_cast<f32x4*>(rowp + c0) = v;
      }
    }
  }
}

extern "C" void kernel_launch(void* const* d_in, const int* in_sizes, int n_in,
                              void* d_out, int out_size, void* d_ws, size_t ws_size,
                              hipStream_t stream) {
  (void)n_in; (void)d_ws; (void)ws_size; (void)out_size;
  const float* X = (const float*)d_in[0];
  float* K = (float*)d_out;
  const int n = in_sizes[0] / DDIM;          // 16384
  dim3 grid(n / 128, n / (128 * JT));        // (128, 16)
  gauss_gram_kernel<<<grid, 256, 0, stream>>>(X, K, n);
}